// Round 4
// baseline (680.004 us; speedup 1.0000x reference)
//
#include <hip/hip_runtime.h>

// Problem dims (fixed): B=8, S=1024, D=512, H=8, AD=64
// Established: float inputs are f32 storage (bf16 reads -> NaN, npz sizes);
// d_out is f32 storage (reference outputs are jnp.float32; bf16-pair writes
// gave finite O(1) error). Comparison is done at bf16 tolerance.
// Internal scratch (projections) kept in bf16 for MFMA.

typedef __attribute__((ext_vector_type(8))) short bf16x8;
typedef __attribute__((ext_vector_type(8))) float f32x8;
typedef __attribute__((ext_vector_type(4))) float f32x4;

#define MFMA16(a, b, c) __builtin_amdgcn_mfma_f32_16x16x32_bf16((a), (b), (c), 0, 0, 0)

__device__ __forceinline__ float b2f(short s) {
    union { unsigned u; float f; } v;
    v.u = ((unsigned)(unsigned short)s) << 16;
    return v.f;
}
__device__ __forceinline__ short f2b(float f) {
    union { float f; unsigned u; } v;
    v.f = f;
    unsigned r = v.u + 0x7fffu + ((v.u >> 16) & 1u);  // RNE
    return (short)(r >> 16);
}

// Load 8 contiguous elements as bf16x8 from either bf16 or f32 storage.
__device__ __forceinline__ bf16x8 ld8(const void* p, long idx, int isbf) {
    if (isbf) return *(const bf16x8*)((const short*)p + idx);
    f32x8 f = *(const f32x8*)((const float*)p + idx);
    bf16x8 r;
#pragma unroll
    for (int j = 0; j < 8; j++) r[j] = f2b(f[j]);
    return r;
}
__device__ __forceinline__ float ld1(const void* p, long idx, int isbf) {
    return isbf ? b2f(((const short*)p)[idx]) : ((const float*)p)[idx];
}

// ---------------------------------------------------------------------------
// Storage sniffer: bits 14-7 of a word are mid-mantissa under f32 storage
// (~16% in [100,140]); the low element's exponent under bf16 storage (~100%).
// ---------------------------------------------------------------------------
__global__ void sniff_dtype(const unsigned* __restrict__ q, int* __restrict__ flag) {
    if (threadIdx.x == 0 && blockIdx.x == 0) {
        int hits = 0;
        for (int i = 0; i < 64; i++) {
            unsigned e = (q[i] >> 7) & 0xFFu;
            hits += (e >= 100u && e <= 140u) ? 1 : 0;
        }
        *flag = (hits > 40) ? 1 : 0;  // 1 = bf16 storage, 0 = f32 storage
    }
}

// ---------------------------------------------------------------------------
// C[8192,512] = A[8192,512] @ W[512,512]^T + bias[512].
// a_dyn: A read via flag (inputs) vs forced-bf16 (our ws buffers).
// c_f32: C written as f32 (final output) vs bf16 (ws).
// Block 256 = 4 waves, block tile 128x128, wave tile 64x64.
// ---------------------------------------------------------------------------
__global__ __launch_bounds__(256) void gemm_xwT(
        const void* __restrict__ A, const void* __restrict__ W,
        const void* __restrict__ bias, void* __restrict__ C,
        const int* __restrict__ flag, int a_dyn, int c_f32) {
    const int isbf = *flag;
    const int a_isbf = a_dyn ? isbf : 1;
    const int bm = blockIdx.x & 63;
    const int bn = blockIdx.x >> 6;
    const int w = threadIdx.x >> 6, lane = threadIdx.x & 63;
    const int m0 = bm * 128 + (w >> 1) * 64;
    const int n0 = bn * 128 + (w & 1) * 64;
    const int lr = lane & 15, lk8 = (lane >> 4) * 8;

    f32x4 acc[4][4] = {};
    for (int kk = 0; kk < 512; kk += 32) {
        bf16x8 a[4], bfr[4];
#pragma unroll
        for (int r = 0; r < 4; r++)
            a[r] = ld8(A, (long)(m0 + r * 16 + lr) * 512 + kk + lk8, a_isbf);
#pragma unroll
        for (int c = 0; c < 4; c++)
            bfr[c] = ld8(W, (long)(n0 + c * 16 + lr) * 512 + kk + lk8, isbf);
#pragma unroll
        for (int r = 0; r < 4; r++)
#pragma unroll
            for (int c = 0; c < 4; c++)
                acc[r][c] = MFMA16(a[r], bfr[c], acc[r][c]);
    }
    const int orow = (lane >> 4) * 4;
#pragma unroll
    for (int c = 0; c < 4; c++) {
        const int col = n0 + c * 16 + lr;
        const float bv = ld1(bias, col, isbf);
#pragma unroll
        for (int r = 0; r < 4; r++)
#pragma unroll
            for (int j = 0; j < 4; j++) {
                const long off = (long)(m0 + r * 16 + orow + j) * 512 + col;
                const float v = acc[r][c][j] + bv;
                if (c_f32) ((float*)C)[off] = v;
                else       ((short*)C)[off] = f2b(v);
            }
    }
}

// ---------------------------------------------------------------------------
// Fused scores + rel-shift + softmax. One block per (b,h,16-q tile).
// LDS f32 sc[16][1024] = 64 KB.
//   BD[q,k] = E[q, 1023+k-q] (k<=q), 0 (k==q+1), E[q+1, k-q-2] (k>=q+2);
//   each sc[q][k] gets exactly one E contribution -> race-free RMW.
// Attn written as f32 (it is part of d_out).
// ---------------------------------------------------------------------------
__global__ __launch_bounds__(256) void attn_scores(
        const short* __restrict__ Q, const short* __restrict__ K,
        const short* __restrict__ R, const void* __restrict__ Ub,
        const void* __restrict__ Vb, const unsigned char* __restrict__ mask,
        float* __restrict__ attn_out, const int* __restrict__ flag) {
    __shared__ float sc[16][1024];  // 64 KB
    const int isbf = *flag;

    const int qt = blockIdx.x & 63;
    const int bh = blockIdx.x >> 6;
    const int b = bh >> 3, h = bh & 7;
    const int q0 = qt * 16;
    const int w = threadIdx.x >> 6, lane = threadIdx.x & 63;
    const int lr = lane & 15, lk8 = (lane >> 4) * 8;

    bf16x8 aU[2], aV0[2], aV1[2];
#pragma unroll
    for (int ks = 0; ks < 2; ks++) {
        const int dof = ks * 32 + lk8;
        {
            bf16x8 qv = *(const bf16x8*)(Q + ((long)(b * 1024 + q0 + lr) * 512) + h * 64 + dof);
            bf16x8 uu, vv;
#pragma unroll
            for (int j = 0; j < 8; j++) {
                float qf = b2f(qv[j]);
                uu[j] = f2b(qf + ld1(Ub, h * 64 + dof + j, isbf));
                vv[j] = f2b(qf + ld1(Vb, h * 64 + dof + j, isbf));
            }
            aU[ks] = uu;
            aV0[ks] = vv;
        }
        {
            int qr = q0 + 16 + lr;
            if (qr > 1023) qr = 1023;  // clamp; boundary values unused
            bf16x8 qv = *(const bf16x8*)(Q + ((long)(b * 1024 + qr) * 512) + h * 64 + dof);
            bf16x8 vv;
#pragma unroll
            for (int j = 0; j < 8; j++)
                vv[j] = f2b(b2f(qv[j]) + ld1(Vb, h * 64 + dof + j, isbf));
            aV1[ks] = vv;
        }
    }

    const long kvbase = (long)(b * 1024) * 512 + h * 64;

    // Phase 1: AC = (Q+U) K^T
    for (int c = w * 16; c < w * 16 + 16; c++) {
        const int k0 = c * 16;
        f32x4 acc = {};
#pragma unroll
        for (int ks = 0; ks < 2; ks++) {
            bf16x8 kf = *(const bf16x8*)(K + kvbase + (long)(k0 + lr) * 512 + ks * 32 + lk8);
            acc = MFMA16(aU[ks], kf, acc);
        }
        const int kcol = k0 + lr;
#pragma unroll
        for (int j = 0; j < 4; j++) sc[(lane >> 4) * 4 + j][kcol] = acc[j];
    }
    __syncthreads();

    // Phase 2: E = (Q+V) R^T with shift-scatter
    for (int c = w * 16; c < w * 16 + 16; c++) {
        const int k0 = c * 16;
        f32x4 e0 = {}, e1 = {};
#pragma unroll
        for (int ks = 0; ks < 2; ks++) {
            bf16x8 rf = *(const bf16x8*)(R + kvbase + (long)(k0 + lr) * 512 + ks * 32 + lk8);
            e0 = MFMA16(aV0[ks], rf, e0);
            e1 = MFMA16(aV1[ks], rf, e1);
        }
        const int jcol = k0 + lr;
#pragma unroll
        for (int j = 0; j < 4; j++) {
            const int r = q0 + (lane >> 4) * 4 + j;
            const int k1 = jcol - 1023 + r;          // rule1 (q=r)
            if (k1 >= 0) sc[r - q0][k1] += e0[j];
            const int k3 = jcol + r + 1;             // rule3 (q=r-1)
            if (r > q0 && k3 <= 1023) sc[r - 1 - q0][k3] += e0[j];
        }
        if ((lane >> 4) == 0) {                      // rule3 for q=q0+15 from row q0+16
            const int k3 = jcol + q0 + 17;
            if (k3 <= 1023) sc[15][k3] += e1[0];
        }
    }
    __syncthreads();

    // Phase 3: softmax per row (16 lanes per row), f32 out
    const int row = threadIdx.x >> 4;
    const int lg = threadIdx.x & 15;
    const unsigned char* mrow = mask + b * 1024;

    float mx = -1e30f;
    for (int i = 0; i < 64; i++) {
        const int k = lg + 16 * i;
        float v = sc[row][k] * 0.125f;
        if (mrow[k]) v -= 1e9f;
        sc[row][k] = v;
        mx = fmaxf(mx, v);
    }
#pragma unroll
    for (int off = 8; off >= 1; off >>= 1) mx = fmaxf(mx, __shfl_xor(mx, off, 16));
    float s = 0.f;
    for (int i = 0; i < 64; i++) {
        const int k = lg + 16 * i;
        float e = __expf(sc[row][k] - mx);
        sc[row][k] = e;
        s += e;
    }
#pragma unroll
    for (int off = 8; off >= 1; off >>= 1) s += __shfl_xor(s, off, 16);
    const float inv = 1.0f / s;

    float* arow = attn_out + ((long)bh * 1024 + q0 + row) * 1024;
    for (int i = 0; i < 64; i++) {
        const int k = lg + 16 * i;
        arow[k] = sc[row][k] * inv;
    }
}

// ---------------------------------------------------------------------------
// Hc[b,q,h,d] = sum_k attn[bh,q,k] * V[b,k,h,d]. attn is f32 (d_out);
// V/Hc are bf16 ws. One block per (bh, 64-q tile).
// ---------------------------------------------------------------------------
__global__ __launch_bounds__(256) void attn_pv(
        const float* __restrict__ attn, const short* __restrict__ V,
        short* __restrict__ Hc) {
    const int qt = blockIdx.x & 15;
    const int bh = blockIdx.x >> 4;
    const int b = bh >> 3, h = bh & 7;
    const int w = threadIdx.x >> 6, lane = threadIdx.x & 63;
    const int q0 = qt * 64 + w * 16;
    const int lr = lane & 15, lk8 = (lane >> 4) * 8;

    const float* abase = attn + (long)bh * 1024 * 1024;
    f32x4 acc[4] = {};
    for (int ks = 0; ks < 32; ks++) {
        f32x8 afl = *(const f32x8*)(abase + (long)(q0 + lr) * 1024 + ks * 32 + lk8);
        bf16x8 af;
#pragma unroll
        for (int j = 0; j < 8; j++) af[j] = f2b(afl[j]);
#pragma unroll
        for (int c = 0; c < 4; c++) {
            bf16x8 vf;
#pragma unroll
            for (int j = 0; j < 8; j++)
                vf[j] = V[(long)(b * 1024 + ks * 32 + lk8 + j) * 512 + h * 64 + c * 16 + lr];
            acc[c] = MFMA16(af, vf, acc[c]);
        }
    }
#pragma unroll
    for (int c = 0; c < 4; c++)
#pragma unroll
        for (int j = 0; j < 4; j++)
            Hc[(long)(b * 1024 + q0 + (lane >> 4) * 4 + j) * 512 + h * 64 + c * 16 + lr] =
                f2b(acc[c][j]);
}

// ---------------------------------------------------------------------------
extern "C" void kernel_launch(void* const* d_in, const int* in_sizes, int n_in,
                              void* d_out, int out_size, void* d_ws, size_t ws_size,
                              hipStream_t stream) {
    const void* query  = d_in[0];
    const void* key    = d_in[1];
    const void* value  = d_in[2];
    const void* relpos = d_in[3];
    const unsigned char* mask = (const unsigned char*)d_in[4];
    const void* Wq = d_in[5];  const void* bq = d_in[6];
    const void* Wk = d_in[7];  const void* bk = d_in[8];
    const void* Wv = d_in[9];  const void* bv = d_in[10];
    const void* Wr = d_in[11]; const void* br = d_in[12];
    const void* Wo = d_in[13]; const void* bo = d_in[14];
    const void* Ub = d_in[15]; const void* Vb = d_in[16];

    float* out  = (float*)d_out;                  // (8,1024,512) f32
    float* attn = out + (long)4194304;            // (64,1024,1024) f32

    short* ws = (short*)d_ws;
    const long NP = 4194304;  // 8192*512
    // ws: Kp | Vp | Rp(->Hc) | flag  (25.2 MB + 4 B), all bf16
    short* Kp = ws;
    short* Vp = ws + NP;
    short* Rp = ws + 2 * NP;
    int* flag = (int*)(ws + 3 * NP);
    short* Qp = (short*)out;  // borrow `out` f32 region (16.8 MB) for bf16 Qp (8.4 MB)
    short* Hc = Rp;           // Rp dead after attn_scores

    sniff_dtype<<<1, 64, 0, stream>>>((const unsigned*)query, flag);

    gemm_xwT<<<256, 256, 0, stream>>>(query, Wq, bq, Qp, flag, 1, 0);
    gemm_xwT<<<256, 256, 0, stream>>>(key, Wk, bk, Kp, flag, 1, 0);
    gemm_xwT<<<256, 256, 0, stream>>>(value, Wv, bv, Vp, flag, 1, 0);
    gemm_xwT<<<256, 256, 0, stream>>>(relpos, Wr, br, Rp, flag, 1, 0);

    attn_scores<<<4096, 256, 0, stream>>>(Qp, Kp, Rp, Ub, Vb, mask, attn, flag);
    attn_pv<<<1024, 256, 0, stream>>>(attn, Vp, Hc);

    gemm_xwT<<<256, 256, 0, stream>>>(Hc, Wo, bo, out, flag, 0, 1);
}

// Round 5
// 469.224 us; speedup vs baseline: 1.4492x; 1.4492x over previous
//
#include <hip/hip_runtime.h>

// B=8, S=1024, D=512, H=8, AD=64. Inputs f32, d_out f32, internal ws bf16.

typedef __attribute__((ext_vector_type(8))) short bf16x8;
typedef __attribute__((ext_vector_type(8))) float f32x8;
typedef __attribute__((ext_vector_type(4))) float f32x4;

#define MFMA16(a, b, c) __builtin_amdgcn_mfma_f32_16x16x32_bf16((a), (b), (c), 0, 0, 0)

__device__ __forceinline__ float b2f(short s) {
    union { unsigned u; float f; } v;
    v.u = ((unsigned)(unsigned short)s) << 16;
    return v.f;
}
__device__ __forceinline__ short f2b(float f) {
    union { float f; unsigned u; } v;
    v.f = f;
    unsigned r = v.u + 0x7fffu + ((v.u >> 16) & 1u);  // RNE
    return (short)(r >> 16);
}
__device__ __forceinline__ bf16x8 ld8(const void* p, long idx, int isbf) {
    if (isbf) return *(const bf16x8*)((const short*)p + idx);
    f32x8 f = *(const f32x8*)((const float*)p + idx);
    bf16x8 r;
#pragma unroll
    for (int j = 0; j < 8; j++) r[j] = f2b(f[j]);
    return r;
}
__device__ __forceinline__ float ld1(const void* p, long idx, int isbf) {
    return isbf ? b2f(((const short*)p)[idx]) : ((const float*)p)[idx];
}

__global__ void sniff_dtype(const unsigned* __restrict__ q, int* __restrict__ flag) {
    if (threadIdx.x == 0 && blockIdx.x == 0) {
        int hits = 0;
        for (int i = 0; i < 64; i++) {
            unsigned e = (q[i] >> 7) & 0xFFu;
            hits += (e >= 100u && e <= 140u) ? 1 : 0;
        }
        *flag = (hits > 40) ? 1 : 0;  // 1 = bf16 storage, 0 = f32 storage
    }
}

// ---------------------------------------------------------------------------
// Shared GEMM body: C[8192,512] = A @ W^T + bias, block tile 128x128,
// 4 waves x (64x64 wave tile), direct-from-global (W is L2-resident).
// ---------------------------------------------------------------------------
__device__ __forceinline__ void gemm_body(
        const void* __restrict__ A, const void* __restrict__ W,
        const void* __restrict__ bias, void* __restrict__ C,
        int bm, int bn, int isbf, int a_isbf, int c_f32) {
    const int w = threadIdx.x >> 6, lane = threadIdx.x & 63;
    const int m0 = bm * 128 + (w >> 1) * 64;
    const int n0 = bn * 128 + (w & 1) * 64;
    const int lr = lane & 15, lk8 = (lane >> 4) * 8;

    f32x4 acc[4][4] = {};
    for (int kk = 0; kk < 512; kk += 32) {
        bf16x8 a[4], bfr[4];
#pragma unroll
        for (int r = 0; r < 4; r++)
            a[r] = ld8(A, (long)(m0 + r * 16 + lr) * 512 + kk + lk8, a_isbf);
#pragma unroll
        for (int c = 0; c < 4; c++)
            bfr[c] = ld8(W, (long)(n0 + c * 16 + lr) * 512 + kk + lk8, isbf);
#pragma unroll
        for (int r = 0; r < 4; r++)
#pragma unroll
            for (int c = 0; c < 4; c++)
                acc[r][c] = MFMA16(a[r], bfr[c], acc[r][c]);
    }
    const int orow = (lane >> 4) * 4;
#pragma unroll
    for (int c = 0; c < 4; c++) {
        const int col = n0 + c * 16 + lr;
        const float bv = ld1(bias, col, isbf);
#pragma unroll
        for (int r = 0; r < 4; r++)
#pragma unroll
            for (int j = 0; j < 4; j++) {
                const long off = (long)(m0 + r * 16 + orow + j) * 512 + col;
                const float v = acc[r][c][j] + bv;
                if (c_f32) ((float*)C)[off] = v;
                else       ((short*)C)[off] = f2b(v);
            }
    }
}

__global__ __launch_bounds__(256) void gemm_xwT(
        const void* __restrict__ A, const void* __restrict__ W,
        const void* __restrict__ bias, void* __restrict__ C,
        const int* __restrict__ flag, int a_dyn, int c_f32) {
    const int isbf = *flag;
    gemm_body(A, W, bias, C, blockIdx.x & 63, blockIdx.x >> 6,
              isbf, a_dyn ? isbf : 1, c_f32);
}

// 4 projection GEMMs in one launch; op pinned to an XCD pair for W locality.
struct P4 { const void* A[4]; const void* W[4]; const void* B[4]; short* C[4]; };
__global__ __launch_bounds__(256) void proj4(P4 p4, const int* __restrict__ flag) {
    const int isbf = *flag;
    const int p = blockIdx.x;                 // 1024 blocks
    const int xcd = p & 7, u = p >> 3;        // u: 0..127
    const int op = xcd >> 1;                  // 2 XCDs per op
    const int idx = (xcd & 1) * 128 + u;      // 0..255 within op
    gemm_body(p4.A[op], p4.W[op], p4.B[op], p4.C[op], idx & 63, idx >> 6,
              isbf, isbf, 0);
}

// ---------------------------------------------------------------------------
// Vt[bh][d][k] = Vp[b][k][h*64+d]  (bf16), LDS 64x64 tile transpose.
// ---------------------------------------------------------------------------
__global__ __launch_bounds__(256) void transpose_v(
        const short* __restrict__ Vp, short* __restrict__ Vt) {
    __shared__ short T[64][72];
    const int bh = blockIdx.x;  // 0..63
    const int b = bh >> 3, h = bh & 7;
    const int t = threadIdx.x;
    const short* src = Vp + (long)b * 1024 * 512 + h * 64;
    short* dst = Vt + (long)bh * 65536;
    for (int kb = 0; kb < 16; kb++) {
        __syncthreads();
#pragma unroll
        for (int it = 0; it < 2; it++) {
            const int row = it * 32 + (t >> 3);
            const int col = (t & 7) * 8;
            *(bf16x8*)&T[row][col] =
                *(const bf16x8*)(src + (long)(kb * 64 + row) * 512 + col);
        }
        __syncthreads();
#pragma unroll
        for (int it = 0; it < 2; it++) {
            const int d = it * 32 + (t >> 3);
            const int kk = (t & 7) * 8;
            bf16x8 v;
#pragma unroll
            for (int e = 0; e < 8; e++) v[e] = T[kk + e][d];
            *(bf16x8*)(dst + (long)d * 1024 + kb * 64 + kk) = v;
        }
    }
}

// ---------------------------------------------------------------------------
// Fused scores + rel-shift + softmax + PV. One block per (b,h,16-q tile),
// XCD-swizzled so all 64 q-tiles of one (b,h) share an XCD (K/R/Vt in L2).
// LDS: f32 sc[16][1028] (pad 4) = 65792 B; reused post-softmax as
// P bf16 [16][1032] (pad 8).
//   BD[q,k] = E[q,1023+k-q] (k<=q), 0 (k==q+1), E[q+1,k-q-2] (k>=q+2);
//   unique source per target -> race-free LDS RMW scatter.
// ---------------------------------------------------------------------------
__global__ __launch_bounds__(256) void attn_scores(
        const short* __restrict__ Q, const short* __restrict__ K,
        const short* __restrict__ R, const short* __restrict__ Vt,
        const void* __restrict__ Ub, const void* __restrict__ Vb,
        const unsigned char* __restrict__ mask,
        float* __restrict__ attn_out, short* __restrict__ Hc,
        const int* __restrict__ flag) {
    __shared__ float sc[16][1028];
    const int isbf = *flag;

    const int p = blockIdx.x;                    // 4096 blocks
    const int xcd = p & 7, u = p >> 3;           // u: 0..511
    const int bh = (u >> 6) * 8 + xcd;           // all qt of one bh on one XCD
    const int qt = u & 63;
    const int b = bh >> 3, h = bh & 7;
    const int q0 = qt * 16;
    const int w = threadIdx.x >> 6, lane = threadIdx.x & 63;
    const int lr = lane & 15, lk8 = (lane >> 4) * 8;

    // A-operand fragments: (Q+U), (Q+V) rows q0..q0+15, (Q+V) rows q0+16..
    bf16x8 aU[2], aV0[2], aV1[2];
#pragma unroll
    for (int ks = 0; ks < 2; ks++) {
        const int dof = ks * 32 + lk8;
        {
            bf16x8 qv = *(const bf16x8*)(Q + ((long)(b * 1024 + q0 + lr) * 512) + h * 64 + dof);
            bf16x8 uu, vv;
#pragma unroll
            for (int j = 0; j < 8; j++) {
                float qf = b2f(qv[j]);
                uu[j] = f2b(qf + ld1(Ub, h * 64 + dof + j, isbf));
                vv[j] = f2b(qf + ld1(Vb, h * 64 + dof + j, isbf));
            }
            aU[ks] = uu;
            aV0[ks] = vv;
        }
        {
            int qr = q0 + 16 + lr;
            if (qr > 1023) qr = 1023;  // clamp; boundary values unused
            bf16x8 qv = *(const bf16x8*)(Q + ((long)(b * 1024 + qr) * 512) + h * 64 + dof);
            bf16x8 vv;
#pragma unroll
            for (int j = 0; j < 8; j++)
                vv[j] = f2b(b2f(qv[j]) + ld1(Vb, h * 64 + dof + j, isbf));
            aV1[ks] = vv;
        }
    }

    const long kvbase = (long)(b * 1024) * 512 + h * 64;

    // Phase 1: AC = (Q+U) K^T
    for (int c = w * 16; c < w * 16 + 16; c++) {
        const int k0 = c * 16;
        f32x4 acc = {};
#pragma unroll
        for (int ks = 0; ks < 2; ks++) {
            bf16x8 kf = *(const bf16x8*)(K + kvbase + (long)(k0 + lr) * 512 + ks * 32 + lk8);
            acc = MFMA16(aU[ks], kf, acc);
        }
        const int kcol = k0 + lr;
#pragma unroll
        for (int j = 0; j < 4; j++) sc[(lane >> 4) * 4 + j][kcol] = acc[j];
    }
    __syncthreads();

    // Phase 2: E = (Q+V) R^T with rel-shift scatter
    for (int c = w * 16; c < w * 16 + 16; c++) {
        const int k0 = c * 16;
        f32x4 e0 = {}, e1 = {};
#pragma unroll
        for (int ks = 0; ks < 2; ks++) {
            bf16x8 rf = *(const bf16x8*)(R + kvbase + (long)(k0 + lr) * 512 + ks * 32 + lk8);
            e0 = MFMA16(aV0[ks], rf, e0);
            e1 = MFMA16(aV1[ks], rf, e1);
        }
        const int jcol = k0 + lr;
#pragma unroll
        for (int j = 0; j < 4; j++) {
            const int r = q0 + (lane >> 4) * 4 + j;
            const int k1 = jcol - 1023 + r;          // rule1 (q=r)
            if (k1 >= 0) sc[r - q0][k1] += e0[j];
            const int k3 = jcol + r + 1;             // rule3 (q=r-1)
            if (r > q0 && k3 <= 1023) sc[r - 1 - q0][k3] += e0[j];
        }
        if ((lane >> 4) == 0) {                      // rule3 for q=q0+15
            const int k3 = jcol + q0 + 17;
            if (k3 <= 1023) sc[15][k3] += e1[0];
        }
    }
    __syncthreads();

    // Phase 3a: register-resident softmax; wave w owns rows 4w..4w+3.
    const unsigned char* mrow = mask + b * 1024;
    unsigned mb[4];
#pragma unroll
    for (int i = 0; i < 4; i++) mb[i] = *(const unsigned*)(mrow + i * 256 + lane * 4);

    f32x4 vv[4][4];
#pragma unroll
    for (int rr = 0; rr < 4; rr++) {
        const int r = w * 4 + rr;
        float mx = -1e30f;
#pragma unroll
        for (int i = 0; i < 4; i++) {
            f32x4 t = *(const f32x4*)&sc[r][i * 256 + lane * 4];
            const unsigned m = mb[i];
#pragma unroll
            for (int j = 0; j < 4; j++) {
                float x = t[j] * 0.125f;
                if ((m >> (8 * j)) & 0xffu) x -= 1e9f;
                t[j] = x;
                mx = fmaxf(mx, x);
            }
            vv[rr][i] = t;
        }
#pragma unroll
        for (int off = 32; off >= 1; off >>= 1) mx = fmaxf(mx, __shfl_xor(mx, off));
        float s = 0.f;
#pragma unroll
        for (int i = 0; i < 4; i++) {
            f32x4 t = vv[rr][i];
#pragma unroll
            for (int j = 0; j < 4; j++) {
                const float e = __expf(t[j] - mx);
                t[j] = e;
                s += e;
            }
            vv[rr][i] = t;
        }
#pragma unroll
        for (int off = 32; off >= 1; off >>= 1) s += __shfl_xor(s, off);
        const float inv = 1.0f / s;

        float* arow = attn_out + ((long)bh * 1024 + q0 + r) * 1024;
#pragma unroll
        for (int i = 0; i < 4; i++) {
            f32x4 t = vv[rr][i];
#pragma unroll
            for (int j = 0; j < 4; j++) t[j] *= inv;
            *(f32x4*)&arow[i * 256 + lane * 4] = t;   // coalesced float4 store
            vv[rr][i] = t;                            // normalized P for PV
        }
    }
    __syncthreads();  // all sc reads complete; LDS region is now free

    // Phase 3b: pack P (bf16, stride 1032) into the reused LDS region.
    short* P = (short*)&sc[0][0];
#pragma unroll
    for (int rr = 0; rr < 4; rr++) {
        const int r = w * 4 + rr;
#pragma unroll
        for (int i = 0; i < 4; i++) {
            const f32x4 t = vv[rr][i];
            union { short s4[4]; unsigned long long u; } pk;
#pragma unroll
            for (int j = 0; j < 4; j++) pk.s4[j] = f2b(t[j]);
            *(unsigned long long*)&P[r * 1032 + i * 256 + lane * 4] = pk.u;
        }
    }
    __syncthreads();

    // Phase 4: PV. Wave w computes d-cols w*16..w*16+15 for all 16 q rows.
    f32x4 acc = {};
    const short* vtb = Vt + (long)bh * 65536 + (long)(w * 16 + lr) * 1024;
    for (int ks = 0; ks < 32; ks++) {
        const bf16x8 a = *(const bf16x8*)&P[lr * 1032 + ks * 32 + lk8];
        const bf16x8 bfr = *(const bf16x8*)(vtb + ks * 32 + lk8);
        acc = MFMA16(a, bfr, acc);
    }
    const int orow = (lane >> 4) * 4;
#pragma unroll
    for (int j = 0; j < 4; j++)
        Hc[(long)(b * 1024 + q0 + orow + j) * 512 + h * 64 + w * 16 + lr] = f2b(acc[j]);
}

// ---------------------------------------------------------------------------
extern "C" void kernel_launch(void* const* d_in, const int* in_sizes, int n_in,
                              void* d_out, int out_size, void* d_ws, size_t ws_size,
                              hipStream_t stream) {
    const void* query  = d_in[0];
    const void* key    = d_in[1];
    const void* value  = d_in[2];
    const void* relpos = d_in[3];
    const unsigned char* mask = (const unsigned char*)d_in[4];
    const void* Wq = d_in[5];  const void* bq = d_in[6];
    const void* Wk = d_in[7];  const void* bk = d_in[8];
    const void* Wv = d_in[9];  const void* bv = d_in[10];
    const void* Wr = d_in[11]; const void* br = d_in[12];
    const void* Wo = d_in[13]; const void* bo = d_in[14];
    const void* Ub = d_in[15]; const void* Vb = d_in[16];

    float* out  = (float*)d_out;                  // (8,1024,512) f32
    float* attn = out + (long)4194304;            // (64,1024,1024) f32

    short* ws = (short*)d_ws;
    const long NP = 4194304;  // 8192*512
    short* Kp = ws;           // bf16
    short* Vp = ws + NP;      // bf16
    short* Rp = ws + 2 * NP;  // bf16
    int* flag = (int*)(ws + 3 * NP);
    short* Qp = (short*)out;            // borrow out region [0, 8.4MB)
    short* Vt = (short*)out + NP;       // borrow out region [8.4, 16.8MB)
    short* Hc = Vp;                     // Vp dead after transpose_v

    sniff_dtype<<<1, 64, 0, stream>>>((const unsigned*)query, flag);

    P4 p4;
    p4.A[0] = query;  p4.W[0] = Wq; p4.B[0] = bq; p4.C[0] = Qp;
    p4.A[1] = key;    p4.W[1] = Wk; p4.B[1] = bk; p4.C[1] = Kp;
    p4.A[2] = value;  p4.W[2] = Wv; p4.B[2] = bv; p4.C[2] = Vp;
    p4.A[3] = relpos; p4.W[3] = Wr; p4.B[3] = br; p4.C[3] = Rp;
    proj4<<<1024, 256, 0, stream>>>(p4, flag);

    transpose_v<<<64, 256, 0, stream>>>(Vp, Vt);

    attn_scores<<<4096, 256, 0, stream>>>(Qp, Kp, Rp, Vt, Ub, Vb, mask,
                                          attn, Hc, flag);

    gemm_xwT<<<256, 256, 0, stream>>>(Hc, Wo, bo, out, flag, 0, 1);
}

// Round 7
// 365.288 us; speedup vs baseline: 1.8616x; 1.2845x over previous
//
#include <hip/hip_runtime.h>

// B=8, S=1024, D=512, H=8, AD=64. Inputs f32 (flag-checked), d_out f32.
// Pipeline: sniff -> convert(inputs+QKVR-weights f32->bf16, stored in dead
// attn region) -> proj4 -> transpose_v -> fused attn (E-row layout, register
// AC+softmax, P-reuse LDS, PV) -> output GEMM (Wo read from original f32:
// the attn write clobbers the converted-weight region!).

typedef __attribute__((ext_vector_type(8))) short bf16x8;
typedef __attribute__((ext_vector_type(8))) float f32x8;
typedef __attribute__((ext_vector_type(4))) float f32x4;

#define MFMA16(a, b, c) __builtin_amdgcn_mfma_f32_16x16x32_bf16((a), (b), (c), 0, 0, 0)

__device__ __forceinline__ float b2f(short s) {
    union { unsigned u; float f; } v;
    v.u = ((unsigned)(unsigned short)s) << 16;
    return v.f;
}
__device__ __forceinline__ short f2b(float f) {
    union { float f; unsigned u; } v;
    v.f = f;
    unsigned r = v.u + 0x7fffu + ((v.u >> 16) & 1u);  // RNE
    return (short)(r >> 16);
}
__device__ __forceinline__ bf16x8 ld8(const void* p, long idx, int isbf) {
    if (isbf) return *(const bf16x8*)((const short*)p + idx);
    f32x8 f = *(const f32x8*)((const float*)p + idx);
    bf16x8 r;
#pragma unroll
    for (int j = 0; j < 8; j++) r[j] = f2b(f[j]);
    return r;
}
__device__ __forceinline__ float ld1(const void* p, long idx, int isbf) {
    return isbf ? b2f(((const short*)p)[idx]) : ((const float*)p)[idx];
}

__global__ void sniff_dtype(const unsigned* __restrict__ q, int* __restrict__ flag) {
    if (threadIdx.x == 0 && blockIdx.x == 0) {
        int hits = 0;
        for (int i = 0; i < 64; i++) {
            unsigned e = (q[i] >> 7) & 0xFFu;
            hits += (e >= 100u && e <= 140u) ? 1 : 0;
        }
        *flag = (hits > 40) ? 1 : 0;  // 1 = bf16 storage, 0 = f32 storage
    }
}

// ---------------------------------------------------------------------------
// One-shot f32->bf16 conversion: 4 big inputs (NP each) + 4 QKVR weights (WN).
// dst: [q|k|v|r] at seg*NP, then [Wq|Wk|Wv|Wr] at 4NP + i*WN.
// 8704 blocks x 256 thr x 8 elems. (Wo NOT converted: its copy would be
// clobbered by the attn f32 write.)
// ---------------------------------------------------------------------------
struct CvtArgs { const void* src[8]; };
__global__ __launch_bounds__(256) void convert_all(
        CvtArgs a, short* __restrict__ dst, const int* __restrict__ flag) {
    const int isbf = *flag;
    const long NP = 4194304, WN = 262144;
    const int bid = blockIdx.x;
    int seg;
    long dstoff, eoff;
    if (bid < 8192) {
        seg = bid >> 11;
        dstoff = (long)seg * NP;
        eoff = (long)(bid & 2047) * 2048 + threadIdx.x * 8;
    } else {
        seg = 4 + ((bid - 8192) >> 7);
        dstoff = 4 * NP + (long)(seg - 4) * WN;
        eoff = (long)((bid - 8192) & 127) * 2048 + threadIdx.x * 8;
    }
    const void* s = a.src[seg];
    if (isbf) {
        *(bf16x8*)(dst + dstoff + eoff) = *(const bf16x8*)((const short*)s + eoff);
    } else {
        f32x8 f = *(const f32x8*)((const float*)s + eoff);
        bf16x8 r;
#pragma unroll
        for (int j = 0; j < 8; j++) r[j] = f2b(f[j]);
        *(bf16x8*)(dst + dstoff + eoff) = r;
    }
}

// ---------------------------------------------------------------------------
// GEMM body: C[8192,512] = A @ W^T + bias. A bf16; W via w_isbf; bias
// flag-read; C bf16 or f32. Block tile 128x128, 4 waves x 64x64.
// ---------------------------------------------------------------------------
__device__ __forceinline__ void gemm_body(
        const short* __restrict__ A, const void* __restrict__ W,
        const void* __restrict__ bias, void* __restrict__ C,
        int bm, int bn, int isbf, int w_isbf, int c_f32) {
    const int w = threadIdx.x >> 6, lane = threadIdx.x & 63;
    const int m0 = bm * 128 + (w >> 1) * 64;
    const int n0 = bn * 128 + (w & 1) * 64;
    const int lr = lane & 15, lk8 = (lane >> 4) * 8;

    f32x4 acc[4][4] = {};
    for (int kk = 0; kk < 512; kk += 32) {
        bf16x8 a[4], bfr[4];
#pragma unroll
        for (int r = 0; r < 4; r++)
            a[r] = *(const bf16x8*)(A + (long)(m0 + r * 16 + lr) * 512 + kk + lk8);
#pragma unroll
        for (int c = 0; c < 4; c++)
            bfr[c] = ld8(W, (long)(n0 + c * 16 + lr) * 512 + kk + lk8, w_isbf);
#pragma unroll
        for (int r = 0; r < 4; r++)
#pragma unroll
            for (int c = 0; c < 4; c++)
                acc[r][c] = MFMA16(a[r], bfr[c], acc[r][c]);
    }
    const int orow = (lane >> 4) * 4;
#pragma unroll
    for (int c = 0; c < 4; c++) {
        const int col = n0 + c * 16 + lr;
        const float bv = ld1(bias, col, isbf);
#pragma unroll
        for (int r = 0; r < 4; r++)
#pragma unroll
            for (int j = 0; j < 4; j++) {
                const long off = (long)(m0 + r * 16 + orow + j) * 512 + col;
                const float v = acc[r][c][j] + bv;
                if (c_f32) ((float*)C)[off] = v;
                else       ((short*)C)[off] = f2b(v);
            }
    }
}

__global__ __launch_bounds__(256) void gemm_xwT(
        const short* __restrict__ A, const void* __restrict__ W,
        const void* __restrict__ bias, void* __restrict__ C,
        const int* __restrict__ flag, int w_dyn, int c_f32) {
    const int isbf = *flag;
    gemm_body(A, W, bias, C, blockIdx.x & 63, blockIdx.x >> 6,
              isbf, w_dyn ? isbf : 1, c_f32);
}

// 4 projection GEMMs in one launch; op pinned to an XCD pair for W locality.
struct P4 { const void* bias[4]; short* C[4]; };
__global__ __launch_bounds__(256) void proj4(
        const short* __restrict__ Sc, P4 p4, const int* __restrict__ flag) {
    const int isbf = *flag;
    const long NP = 4194304, WN = 262144;
    const int p = blockIdx.x;                 // 1024 blocks
    const int xcd = p & 7, u = p >> 3;        // u: 0..127
    const int op = xcd >> 1;                  // 2 XCDs per op
    const int idx = (xcd & 1) * 128 + u;      // 0..255 within op
    gemm_body(Sc + (long)op * NP, Sc + 4 * NP + (long)op * WN,
              p4.bias[op], p4.C[op], idx & 63, idx >> 6, isbf, 1, 0);
}

// ---------------------------------------------------------------------------
// Vt[bh][d][k] = Vp[b][k][h*64+d]  (bf16), LDS 64x64 tile transpose.
// 256 blocks: 4 blocks per bh, 4 k-tiles each.
// ---------------------------------------------------------------------------
__global__ __launch_bounds__(256) void transpose_v(
        const short* __restrict__ Vp, short* __restrict__ Vt) {
    __shared__ short T[64][72];
    const int bh = blockIdx.x >> 2;
    const int kq = blockIdx.x & 3;
    const int b = bh >> 3, h = bh & 7;
    const int t = threadIdx.x;
    const short* src = Vp + (long)b * 1024 * 512 + h * 64;
    short* dst = Vt + (long)bh * 65536;
    for (int kb = kq * 4; kb < kq * 4 + 4; kb++) {
        __syncthreads();
#pragma unroll
        for (int it = 0; it < 2; it++) {
            const int row = it * 32 + (t >> 3);
            const int col = (t & 7) * 8;
            *(bf16x8*)&T[row][col] =
                *(const bf16x8*)(src + (long)(kb * 64 + row) * 512 + col);
        }
        __syncthreads();
#pragma unroll
        for (int it = 0; it < 2; it++) {
            const int d = it * 32 + (t >> 3);
            const int kk = (t & 7) * 8;
            bf16x8 v;
#pragma unroll
            for (int e = 0; e < 8; e++) v[e] = T[kk + e][d];
            *(bf16x8*)(dst + (long)d * 1024 + kb * 64 + kk) = v;
        }
    }
}

// ---------------------------------------------------------------------------
// Fused scores + rel-shift + softmax + PV, E-row layout (no scatter).
// One block per (b,h,16-q tile), XCD-swizzled per (b,h).
// LDS: E bf16 [17][1032] (35.1 KB, reused for P[16][1048]) + partials.
//   BD[r][c] = E_flat[r*1032 + dq + (dq<=0 ? 1023 : 1030)], dq = c-q0-r,
//   zero at dq==1 (stale read lands in row padding, in-bounds).
// ---------------------------------------------------------------------------
__global__ __launch_bounds__(256, 4) void attn_fused(
        const short* __restrict__ Q, const short* __restrict__ K,
        const short* __restrict__ R, const short* __restrict__ Vt,
        const void* __restrict__ Ub, const void* __restrict__ Vb,
        const unsigned char* __restrict__ mask,
        float* __restrict__ attn_out, short* __restrict__ Hc,
        const int* __restrict__ flag) {
    __shared__ __align__(16) short Esh[17 * 1032];  // P[16][1048] fits inside
    __shared__ float redmx[4][16];
    __shared__ float redsm[4][16];
    const int isbf = *flag;

    const int p = blockIdx.x;                    // 4096 blocks
    const int xcd = p & 7, u = p >> 3;
    const int bh = (u >> 6) * 8 + xcd;           // all qt of one bh on one XCD
    const int qt = u & 63;
    const int b = bh >> 3, h = bh & 7;
    const int q0 = qt * 16;
    const int w = threadIdx.x >> 6, lane = threadIdx.x & 63;
    const int lr = lane & 15, lg = lane >> 4, lk8 = lg * 8;

    const long kvbase = (long)(b * 1024) * 512 + h * 64;

    // ---- Phase A: E rows q0..q0+16 -> Esh (linear, race-free) ----
    {
        bf16x8 aV0[2], aV1[2];
#pragma unroll
        for (int ks = 0; ks < 2; ks++) {
            const int dof = ks * 32 + lk8;
            bf16x8 qv = *(const bf16x8*)(Q + (long)(b * 1024 + q0 + lr) * 512 + h * 64 + dof);
            int qr = q0 + 16 + lr;
            if (qr > 1023) qr = 1023;  // clamp; values unread at boundary
            bf16x8 qv1 = *(const bf16x8*)(Q + (long)(b * 1024 + qr) * 512 + h * 64 + dof);
#pragma unroll
            for (int j = 0; j < 8; j++) {
                const float vbj = ld1(Vb, h * 64 + dof + j, isbf);
                aV0[ks][j] = f2b(b2f(qv[j]) + vbj);
                aV1[ks][j] = f2b(b2f(qv1[j]) + vbj);
            }
        }
        for (int tt = 0; tt < 16; tt++) {
            const int k0 = (w * 16 + tt) * 16;
            f32x4 e0 = {}, e1 = {};
#pragma unroll
            for (int ks = 0; ks < 2; ks++) {
                bf16x8 rf = *(const bf16x8*)(R + kvbase + (long)(k0 + lr) * 512 + ks * 32 + lk8);
                e0 = MFMA16(aV0[ks], rf, e0);
                e1 = MFMA16(aV1[ks], rf, e1);
            }
            const int jcol = k0 + lr;
#pragma unroll
            for (int j = 0; j < 4; j++)
                Esh[(lg * 4 + j) * 1032 + jcol] = f2b(e0[j]);
            if (lg == 0) Esh[16 * 1032 + jcol] = f2b(e1[0]);  // E row q0+16
        }
    }
    __syncthreads();

    // ---- Phase B: AC (registers) + gathered BD + scale + mask ----
    f32x4 acc[16];
    {
        bf16x8 aU[2];
#pragma unroll
        for (int ks = 0; ks < 2; ks++) {
            const int dof = ks * 32 + lk8;
            bf16x8 qv = *(const bf16x8*)(Q + (long)(b * 1024 + q0 + lr) * 512 + h * 64 + dof);
#pragma unroll
            for (int j = 0; j < 8; j++)
                aU[ks][j] = f2b(b2f(qv[j]) + ld1(Ub, h * 64 + dof + j, isbf));
        }
        const unsigned char* mrow = mask + b * 1024;
#pragma unroll
        for (int tt = 0; tt < 16; tt++) {
            const int k0 = (w * 16 + tt) * 16;
            f32x4 a = {};
#pragma unroll
            for (int ks = 0; ks < 2; ks++) {
                bf16x8 kf = *(const bf16x8*)(K + kvbase + (long)(k0 + lr) * 512 + ks * 32 + lk8);
                a = MFMA16(aU[ks], kf, a);
            }
            const int c = k0 + lr;
            const float mbias = mrow[c] ? -1e9f : 0.0f;
#pragma unroll
            for (int j = 0; j < 4; j++) {
                const int r = lg * 4 + j;
                const int dq = c - q0 - r;
                const int idx = r * 1032 + dq + ((dq <= 0) ? 1023 : 1030);
                float bd = b2f(Esh[idx]);
                if (dq == 1) bd = 0.0f;
                a[j] = (a[j] + bd) * 0.125f + mbias;
            }
            acc[tt] = a;
        }
    }

    // ---- softmax (register-resident; cross-wave via tiny LDS partials) ----
    float mx[4], sm[4];
#pragma unroll
    for (int j = 0; j < 4; j++) {
        float m = -1e30f;
#pragma unroll
        for (int tt = 0; tt < 16; tt++) m = fmaxf(m, acc[tt][j]);
#pragma unroll
        for (int off = 1; off <= 8; off <<= 1) m = fmaxf(m, __shfl_xor(m, off));
        mx[j] = m;
    }
    if (lr == 0) {
#pragma unroll
        for (int j = 0; j < 4; j++) redmx[w][lg * 4 + j] = mx[j];
    }
    __syncthreads();
#pragma unroll
    for (int j = 0; j < 4; j++) {
        float m = redmx[0][lg * 4 + j];
#pragma unroll
        for (int ww = 1; ww < 4; ww++) m = fmaxf(m, redmx[ww][lg * 4 + j]);
        mx[j] = m;
        sm[j] = 0.0f;
    }
#pragma unroll
    for (int tt = 0; tt < 16; tt++)
#pragma unroll
        for (int j = 0; j < 4; j++) {
            const float e = __expf(acc[tt][j] - mx[j]);
            acc[tt][j] = e;
            sm[j] += e;
        }
#pragma unroll
    for (int j = 0; j < 4; j++) {
        float s = sm[j];
#pragma unroll
        for (int off = 1; off <= 8; off <<= 1) s += __shfl_xor(s, off);
        sm[j] = s;
    }
    if (lr == 0) {
#pragma unroll
        for (int j = 0; j < 4; j++) redsm[w][lg * 4 + j] = sm[j];
    }
    __syncthreads();  // also: all Esh (E) reads complete beyond this point
    float inv[4];
#pragma unroll
    for (int j = 0; j < 4; j++) {
        float s = redsm[0][lg * 4 + j];
#pragma unroll
        for (int ww = 1; ww < 4; ww++) s += redsm[ww][lg * 4 + j];
        inv[j] = 1.0f / s;
    }

    // ---- P pack: bf16 [16][1048] into the Esh region ----
    short* P = Esh;
#pragma unroll
    for (int tt = 0; tt < 16; tt++) {
        const int c = (w * 16 + tt) * 16 + lr;
#pragma unroll
        for (int j = 0; j < 4; j++)
            P[(lg * 4 + j) * 1048 + c] = f2b(acc[tt][j] * inv[j]);
    }
    __syncthreads();

    // ---- attn f32 output from P (coalesced) ----
    float* abase = attn_out + ((long)bh * 1024 + q0) * 1024;
#pragma unroll
    for (int rr = 0; rr < 4; rr++) {
        const int r = w * 4 + rr;
#pragma unroll
        for (int half = 0; half < 2; half++) {
            const bf16x8 pv8 = *(const bf16x8*)&P[r * 1048 + half * 512 + lane * 8];
            f32x4 lo, hi;
#pragma unroll
            for (int e = 0; e < 4; e++) { lo[e] = b2f(pv8[e]); hi[e] = b2f(pv8[4 + e]); }
            float* dst = abase + (long)r * 1024 + half * 512 + lane * 8;
            *(f32x4*)dst = lo;
            *(f32x4*)(dst + 4) = hi;
        }
    }

    // ---- PV: wave w computes d-cols w*16..+15 for all 16 q rows ----
    f32x4 oacc = {};
    const short* vtb = Vt + (long)bh * 65536 + (long)(w * 16 + lr) * 1024;
    for (int ks = 0; ks < 32; ks++) {
        const bf16x8 aa = *(const bf16x8*)&P[lr * 1048 + ks * 32 + lk8];
        const bf16x8 bb = *(const bf16x8*)(vtb + ks * 32 + lk8);
        oacc = MFMA16(aa, bb, oacc);
    }
#pragma unroll
    for (int j = 0; j < 4; j++)
        Hc[(long)(b * 1024 + q0 + lg * 4 + j) * 512 + h * 64 + w * 16 + lr] = f2b(oacc[j]);
}

// ---------------------------------------------------------------------------
extern "C" void kernel_launch(void* const* d_in, const int* in_sizes, int n_in,
                              void* d_out, int out_size, void* d_ws, size_t ws_size,
                              hipStream_t stream) {
    const void* query  = d_in[0];
    const void* key    = d_in[1];
    const void* value  = d_in[2];
    const void* relpos = d_in[3];
    const unsigned char* mask = (const unsigned char*)d_in[4];
    const void* Wq = d_in[5];  const void* bq = d_in[6];
    const void* Wk = d_in[7];  const void* bk = d_in[8];
    const void* Wv = d_in[9];  const void* bv = d_in[10];
    const void* Wr = d_in[11]; const void* br = d_in[12];
    const void* Wo = d_in[13]; const void* bo = d_in[14];
    const void* Ub = d_in[15]; const void* Vb = d_in[16];

    float* out  = (float*)d_out;                  // (8,1024,512) f32
    float* attn = out + (long)4194304;            // (64,1024,1024) f32

    const long NP = 4194304;
    short* ws = (short*)d_ws;
    short* Kp = ws;           // bf16
    short* Vp = ws + NP;      // bf16
    short* Rp = ws + 2 * NP;  // bf16
    int* flag = (int*)(ws + 3 * NP);
    short* Qp = (short*)out;            // out region [0, 8.4MB)
    short* Vt = (short*)out + NP;       // out region [8.4, 16.8MB)
    short* Hc = Vp;                     // Vp dead after transpose_v
    short* Sc = (short*)attn;           // converted bf16 (dead once attn
                                        // region is written by attn_fused)

    sniff_dtype<<<1, 64, 0, stream>>>((const unsigned*)query, flag);

    CvtArgs ca;
    ca.src[0] = query; ca.src[1] = key; ca.src[2] = value; ca.src[3] = relpos;
    ca.src[4] = Wq; ca.src[5] = Wk; ca.src[6] = Wv; ca.src[7] = Wr;
    convert_all<<<8704, 256, 0, stream>>>(ca, Sc, flag);

    P4 p4;
    p4.bias[0] = bq; p4.C[0] = Qp;
    p4.bias[1] = bk; p4.C[1] = Kp;
    p4.bias[2] = bv; p4.C[2] = Vp;
    p4.bias[3] = br; p4.C[3] = Rp;
    proj4<<<1024, 256, 0, stream>>>(Sc, p4, flag);

    transpose_v<<<256, 256, 0, stream>>>(Vp, Vt);

    attn_fused<<<4096, 256, 0, stream>>>(Qp, Kp, Rp, Vt, Ub, Vb, mask,
                                         attn, Hc, flag);

    // Wo read from the ORIGINAL f32 input (converted copy was clobbered).
    gemm_xwT<<<256, 256, 0, stream>>>(Hc, Wo, bo, out, flag, 1, 1);
}